// Round 2
// baseline (198070.959 us; speedup 1.0000x reference)
//
#include <hip/hip_runtime.h>

// ============================================================================
// samba_hemo_to_ele: ConvT1d+GELU+BN -> 2-layer LSTM (T=6000 scan) -> MLP
// Round 2: SINGLE merged chain block (both LSTM layers, weights in VGPRs),
// chunked (64-step) flag protocol, static C-worker assignment, hoisted conv.
// ============================================================================

#define DEV static __device__ __forceinline__

typedef short s16x8 __attribute__((ext_vector_type(8)));
typedef float f32x4 __attribute__((ext_vector_type(4)));

#define TCONV 1000
#define TT 6000
#define KP 224        // padded K (7 chunks of 32)
#define XROW 240      // LDS h row pad
#define RING 512      // pre1 ring slots
#define CH 64         // chunk size (steps)
#define NCHUNK 94     // ceil(6000/64)
#define NPRE 14
#define NC 16
#define ZROW 808      // zbuf row pad (dwords)
#define LDS_BYTES 147584

DEV short f2bf(float f) {
    unsigned u = __builtin_bit_cast(unsigned, f);
    unsigned r = (u + 0x7FFFu + ((u >> 16) & 1u)) >> 16;
    return (short)r;
}
DEV unsigned ld_acq(const unsigned* p) { return __hip_atomic_load(p, __ATOMIC_ACQUIRE, __HIP_MEMORY_SCOPE_AGENT); }
DEV void st_rel(unsigned* p, unsigned v) { __hip_atomic_store(p, v, __ATOMIC_RELEASE, __HIP_MEMORY_SCOPE_AGENT); }
DEV f32x4 mfma16(s16x8 a, s16x8 b, f32x4 c) { return __builtin_amdgcn_mfma_f32_16x16x32_bf16(a, b, c, 0, 0, 0); }
DEV float sigm(float x) { return 1.f / (1.f + __expf(-x)); }
DEV float tanh_fast(float x) {
    float ax = fabsf(x);
    float e = __expf(-2.f * ax);
    float r = 1.f - 2.f * e / (1.f + e);
    return copysignf(r, x);
}

// ============================ K1: ConvTranspose + GELU =====================
__global__ __launch_bounds__(256) void k_conv(const float* __restrict__ x,
                                              const float* __restrict__ w,
                                              const float* __restrict__ cb,
                                              float* __restrict__ y) {
    __shared__ float ws_[8][32][30];
    __shared__ float xs[8][38];
    const int tt = blockIdx.x, ot = blockIdx.y, b = blockIdx.z;
    const int tid = threadIdx.x;
    const int o_l = tid & 31, tq = tid >> 5;
    const int o = ot * 32 + o_l;
    const int T0base = tt * 32;
    float acc[24];
#pragma unroll
    for (int u = 0; u < 24; u++) acc[u] = 0.f;
    for (int ic = 0; ic < 200; ic += 8) {
        __syncthreads();
        for (int idx = tid; idx < 7680; idx += 256) {
            int ii = idx / 960, rem = idx % 960, oo = rem / 30, kk = rem % 30;
            int og = ot * 32 + oo;
            ws_[ii][oo][kk] = (og < 200) ? w[((size_t)(ic + ii) * 200 + og) * 30 + kk] : 0.f;
        }
        for (int idx = tid; idx < 8 * 36; idx += 256) {
            int ii = idx / 36, m = idx % 36;
            int ti = T0base - 2 + m;
            xs[ii][m] = (ti >= 0 && ti < TCONV) ? x[((size_t)b * 200 + ic + ii) * TCONV + ti] : 0.f;
        }
        __syncthreads();
#pragma unroll
        for (int ii = 0; ii < 8; ii++) {
            float xr[8];
#pragma unroll
            for (int m = 0; m < 8; m++) xr[m] = xs[ii][tq * 4 + m];
#pragma unroll
            for (int r = 0; r < 6; r++) {
#pragma unroll
                for (int j = 0; j < 5; j++) {
                    float wv_ = ws_[ii][o_l][r + 6 * j];
#pragma unroll
                    for (int k = 0; k < 4; k++) acc[r + 6 * k] += xr[k + 4 - j] * wv_;
                }
            }
        }
    }
    if (o < 200) {
        const float bias = cb[o];
        const int tob = tt * 192 + tq * 24;
#pragma unroll
        for (int u = 0; u < 24; u++) {
            int t_o = tob + u;
            if (t_o < TT) {
                float v = acc[u] + bias;
                v = 0.5f * v * (1.f + erff(v * 0.70710678118654752f));
                y[((size_t)b * 200 + o) * TT + t_o] = v;
            }
        }
    }
}

// ============================ K2: BN stats =================================
__global__ __launch_bounds__(256) void k_stats(const float* __restrict__ y,
                                               const float* __restrict__ g,
                                               const float* __restrict__ be,
                                               float* __restrict__ scale,
                                               float* __restrict__ shift) {
    __shared__ float s1[256], s2[256];
    const int c = blockIdx.x, tid = threadIdx.x;
    float a1 = 0.f, a2 = 0.f;
    for (int idx = tid; idx < 16 * TT; idx += 256) {
        int b = idx / TT, t = idx % TT;
        float v = y[((size_t)b * 200 + c) * TT + t];
        a1 += v;
        a2 += v * v;
    }
    s1[tid] = a1; s2[tid] = a2;
    __syncthreads();
    for (int s = 128; s > 0; s >>= 1) {
        if (tid < s) { s1[tid] += s1[tid + s]; s2[tid] += s2[tid + s]; }
        __syncthreads();
    }
    if (tid == 0) {
        float mean = s1[0] / (float)(16 * TT);
        float var = s2[0] / (float)(16 * TT) - mean * mean;
        float istd = rsqrtf(var + 1e-5f);
        float sc = g[c] * istd;
        scale[c] = sc;
        shift[c] = be[c] - mean * sc;
    }
}

// ==================== K3: BN-apply + transpose + bf16 cast =================
__global__ __launch_bounds__(256) void k_transpose(const float* __restrict__ y,
                                                   const float* __restrict__ scale,
                                                   const float* __restrict__ shift,
                                                   short* __restrict__ xhatT) {
    __shared__ float tile[32][65];
    const int tt = blockIdx.x, ct = blockIdx.y, b = blockIdx.z;
    const int tid = threadIdx.x;
    for (int idx = tid; idx < 2048; idx += 256) {
        int c_l = idx >> 6, t_l = idx & 63;
        int c = ct * 32 + c_l, t = tt * 64 + t_l;
        float v = 0.f;
        if (c < 200 && t < TT) v = y[((size_t)b * 200 + c) * TT + t] * scale[c] + shift[c];
        tile[c_l][t_l] = v;
    }
    __syncthreads();
    {
        int t_l = tid >> 2, cq = tid & 3;
        int t = tt * 64 + t_l;
        if (t < TT) {
            short tmp[8];
#pragma unroll
            for (int jj = 0; jj < 8; jj++) tmp[jj] = f2bf(tile[cq * 8 + jj][t_l]);
            *(uint4*)&xhatT[((size_t)t * 16 + b) * KP + ct * 32 + cq * 8] = *(uint4*)tmp;
        }
    }
}

// ==================== K3b: weight prep (permute n'=4j+g, bf16, pad) ========
__global__ void k_prep(const float* wi0, const float* wh0, const float* wi1, const float* wh1,
                       const float* bi0, const float* bh0, const float* bi1, const float* bh1,
                       const float* o1w, const float* o1b, const float* o2w,
                       short* Wi0p, short* Wh0p, short* Wi1p, short* Wh1p,
                       float* b1p, float* b2p, short* o1wp, float* o1bp, short* o2wp) {
    const int TOT = 716800 + 1600 + 25088 + 26624 + 112;
    int i = blockIdx.x * blockDim.x + threadIdx.x;
    int st = gridDim.x * blockDim.x;
    for (; i < TOT; i += st) {
        if (i < 716800) {
            int m = i / 179200, r = i % 179200;
            int np = r / KP, k = r % KP;
            int j = np >> 2, gg = np & 3;
            int row = gg * 200 + j;
            const float* src = (m == 0) ? wi0 : (m == 1) ? wh0 : (m == 2) ? wi1 : wh1;
            short* dst = (m == 0) ? Wi0p : (m == 1) ? Wh0p : (m == 2) ? Wi1p : Wh1p;
            dst[np * KP + k] = (k < 200) ? f2bf(src[row * 200 + k]) : (short)0;
        } else if (i < 718400) {
            int r = i - 716800;
            int which = r / 800, np = r % 800;
            int j = np >> 2, gg = np & 3;
            int row = gg * 200 + j;
            if (which == 0) b1p[np] = bi0[row] + bh0[row];
            else b2p[np] = bi1[row] + bh1[row];
        } else if (i < 743488) {
            int r = i - 718400;
            int o = r / KP, k = r % KP;
            o1wp[o * KP + k] = (o < 100 && k < 200) ? f2bf(o1w[o * 200 + k]) : (short)0;
        } else if (i < 770112) {
            int r = i - 743488;
            int p = r / 128, k = r % 128;
            o2wp[p * 128 + k] = (p < 200 && k < 100) ? f2bf(o2w[p * 100 + k]) : (short)0;
        } else {
            int o = i - 770112;
            o1bp[o] = (o < 100) ? o1b[o] : 0.f;
        }
    }
}

__global__ void k_init(unsigned* p, int n) {
    int i = blockIdx.x * blockDim.x + threadIdx.x;
    int st = gridDim.x * blockDim.x;
    for (; i < n; i += st) p[i] = 0;
}

// ============================ pipeline =====================================
struct PipeArgs {
    const short *Wih0, *Whh0, *Wih1, *Whh1, *o1w, *o2w;
    const float *b1p, *b2p, *o1b, *o2b;
    const short* xhatT;
    const float* xmeg;
    float* pre1;     // ring [RING][16][800] f32 (x-side of layer1 + bias1)
    short* h2full;   // [6000][16][224] bf16
    unsigned* flags; // [0..93] pre-chunk done, [94] chain_prog
    const float *h0, *c0;
    float* out;
};

// ---- merged 2-layer LSTM chain, 1024 threads, all 150 weight tiles in regs
DEV void chain_run(const PipeArgs& P, char* lds) {
    short* X1 = (short*)lds;                    // [16][240] bf16 (h1)
    short* X2 = (short*)(lds + 7680);           // [16][240] bf16 (h2)
    float* c1 = (float*)(lds + 15360);          // [16][200]
    float* c2 = (float*)(lds + 28160);          // [16][200]
    float* bias2 = (float*)(lds + 40960);       // [800]
    float* zb1 = (float*)(lds + 44160);         // [16][808]
    float* zb2 = (float*)(lds + 95872);         // [16][808]
    const int tid = threadIdx.x;
    const int wv = tid >> 6, lane = tid & 63;
    const int col = lane & 15, quad = lane >> 4;

    for (int i = tid; i < 16 * XROW; i += 1024) { int j = i % XROW; X1[i] = (j < 200) ? f2bf(P.h0[j]) : (short)0; }
    for (int i = tid; i < 16 * XROW; i += 1024) { int j = i % XROW; X2[i] = (j < 200) ? f2bf(P.h0[200 + j]) : (short)0; }
    for (int i = tid; i < 3200; i += 1024) c1[i] = P.c0[i % 200];
    for (int i = tid; i < 3200; i += 1024) c2[i] = P.c0[200 + (i % 200)];
    if (tid < 800) bias2[tid] = P.b2p[tid];

    // slot s: global tile g = wv + 16s. g<50: Whh0 (z1h). 50<=g<100: Whh1 (z2h).
    // 100<=g<150: Wih1 (z2x, phase B). g>=150: dead (zero weights).
    s16x8 wf[10][7];
#pragma unroll
    for (int s = 0; s < 10; s++) {
        int g = wv + 16 * s;
        const short* Wm = (g < 50) ? P.Whh0 : (g < 100) ? P.Whh1 : P.Wih1;
        int tl = (g < 50) ? g : (g < 100) ? g - 50 : g - 100;
#pragma unroll
        for (int kc = 0; kc < 7; kc++) {
            if (g < 150) wf[s][kc] = *(const s16x8*)(Wm + ((size_t)(tl * 16 + col)) * KP + kc * 32 + quad * 8);
            else wf[s][kc] = (s16x8){0, 0, 0, 0, 0, 0, 0, 0};
        }
    }
    __syncthreads();

    unsigned* chain_prog = P.flags + NCHUNK;
    for (int t = 0; t < TT; t++) {
        if ((t & 63) == 0) {
            if (tid == 0) {
                while (ld_acq(&P.flags[t >> 6]) == 0) __builtin_amdgcn_s_sleep(16);
            }
            __syncthreads();
        }
        // prefetch pre1[t] (consumed in gates L1, ~1500cy later)
        const float* zin = P.pre1 + (size_t)(t & (RING - 1)) * 12800;
        float4 pz[4];
#pragma unroll
        for (int i = 0; i < 4; i++) {
            int idx = tid + 1024 * i;
            if (idx < 3200) pz[i] = *(const float4*)(zin + idx * 4);
        }
        // ---- phase A: z1h = X1@Whh0^T, z2h = X2@Whh1^T
        f32x4 acc[10];
#pragma unroll
        for (int s = 0; s < 10; s++) acc[s] = (f32x4){0.f, 0.f, 0.f, 0.f};
#pragma unroll
        for (int kc = 0; kc < 7; kc++) {
            s16x8 a1 = *(const s16x8*)&X1[col * XROW + kc * 32 + quad * 8];
            s16x8 a2 = *(const s16x8*)&X2[col * XROW + kc * 32 + quad * 8];
#pragma unroll
            for (int s = 0; s < 10; s++) {
                int g = wv + 16 * s;
                if (g < 50) acc[s] = mfma16(a1, wf[s][kc], acc[s]);
                else if (g < 100) acc[s] = mfma16(a2, wf[s][kc], acc[s]);
            }
        }
#pragma unroll
        for (int s = 0; s < 10; s++) {
            int g = wv + 16 * s;
            if (g < 50) {
#pragma unroll
                for (int r = 0; r < 4; r++) zb1[(quad * 4 + r) * ZROW + g * 16 + col] = acc[s][r];
            } else if (g < 100) {
#pragma unroll
                for (int r = 0; r < 4; r++) zb2[(quad * 4 + r) * ZROW + (g - 50) * 16 + col] = acc[s][r];
            }
        }
        __syncthreads();  // S1
        // ---- gates L1 -> h1 (X1), c1
#pragma unroll
        for (int i = 0; i < 4; i++) {
            int idx = tid + 1024 * i;
            if (idx < 3200) {
                int b = idx / 200, j = idx % 200;
                float4 z4 = *(const float4*)&zb1[b * ZROW + j * 4];
                float4 p4 = pz[i];
                float ig = sigm(z4.x + p4.x);
                float fg = sigm(z4.y + p4.y);
                float gg = tanh_fast(z4.z + p4.z);
                float og = sigm(z4.w + p4.w);
                float c = fg * c1[b * 200 + j] + ig * gg;
                c1[b * 200 + j] = c;
                X1[b * XROW + j] = f2bf(og * tanh_fast(c));
            }
        }
        __syncthreads();  // S2
        // ---- phase B: z2x = h1@Wih1^T, accumulate into zb2
        f32x4 accB[4];
#pragma unroll
        for (int s = 0; s < 4; s++) accB[s] = (f32x4){0.f, 0.f, 0.f, 0.f};
#pragma unroll
        for (int kc = 0; kc < 7; kc++) {
            s16x8 ah = *(const s16x8*)&X1[col * XROW + kc * 32 + quad * 8];
#pragma unroll
            for (int s = 0; s < 4; s++) {
                int g = wv + 16 * (s + 6);
                if (g >= 100 && g < 150) accB[s] = mfma16(ah, wf[s + 6][kc], accB[s]);
            }
        }
#pragma unroll
        for (int s = 0; s < 4; s++) {
            int g = wv + 16 * (s + 6);
            if (g >= 100 && g < 150) {
                int tl = g - 100;
#pragma unroll
                for (int r = 0; r < 4; r++) {
                    int a = (quad * 4 + r) * ZROW + tl * 16 + col;
                    zb2[a] += accB[s][r];
                }
            }
        }
        __syncthreads();  // S3
        // ---- gates L2 -> h2 (X2), c2
#pragma unroll
        for (int i = 0; i < 4; i++) {
            int idx = tid + 1024 * i;
            if (idx < 3200) {
                int b = idx / 200, j = idx % 200;
                float4 z4 = *(const float4*)&zb2[b * ZROW + j * 4];
                float4 b4 = *(const float4*)&bias2[j * 4];
                float ig = sigm(z4.x + b4.x);
                float fg = sigm(z4.y + b4.y);
                float gg = tanh_fast(z4.z + b4.z);
                float og = sigm(z4.w + b4.w);
                float c = fg * c2[b * 200 + j] + ig * gg;
                c2[b * 200 + j] = c;
                X2[b * XROW + j] = f2bf(og * tanh_fast(c));
            }
        }
        __syncthreads();  // S4
        // ---- h2 -> global
        short* dst = P.h2full + (size_t)t * 3584;
        if (tid < 448) {
            int b = tid / 28, cc = tid % 28;
            *(uint4*)(dst + b * 224 + cc * 8) = *(const uint4*)(X2 + b * XROW + cc * 8);
        }
        if (((t + 1) & 63) == 0 || t == TT - 1) {
            __syncthreads();
            if (tid == 0) { __threadfence(); st_rel(chain_prog, (unsigned)(t + 1)); }
        }
    }
}

// ---- pre1 worker: pre1[t] = inputs[t] @ Wih0^T + bias1 (weights in regs)
DEV void pre_run(const PipeArgs& P, int wid) {
    const int tid = threadIdx.x;
    const int wv = tid >> 6, lane = tid & 63;
    const int col = lane & 15, quad = lane >> 4;
    s16x8 wf[4][7];
#pragma unroll
    for (int s = 0; s < 4; s++) {
        int g = wv + 16 * s;
#pragma unroll
        for (int kc = 0; kc < 7; kc++) {
            if (g < 50) wf[s][kc] = *(const s16x8*)(P.Wih0 + ((size_t)(g * 16 + col)) * KP + kc * 32 + quad * 8);
            else wf[s][kc] = (s16x8){0, 0, 0, 0, 0, 0, 0, 0};
        }
    }
    unsigned* chain_prog = P.flags + NCHUNK;
    for (int q = wid; q < NCHUNK; q += NPRE) {
        int lim = CH * q - (RING - CH);  // ring-space window
        if (lim > 0) {
            if (tid == 0) {
                while ((int)ld_acq(chain_prog) < lim) __builtin_amdgcn_s_sleep(64);
            }
            __syncthreads();
        }
        int t0 = q * CH, te = min(TT, t0 + CH);
        for (int t = t0; t < te; t++) {
            s16x8 af[7];
            if (t > 0) {
                const short* xr = P.xhatT + (size_t)(t - 1) * 3584;
#pragma unroll
                for (int kc = 0; kc < 7; kc++)
                    af[kc] = *(const s16x8*)(xr + col * KP + kc * 32 + quad * 8);
            } else {
#pragma unroll
                for (int kc = 0; kc < 7; kc++) {
                    s16x8 v;
#pragma unroll
                    for (int j = 0; j < 8; j++) {
                        int k = kc * 32 + quad * 8 + j;
                        v[j] = (k < 200) ? f2bf(P.xmeg[((size_t)col * 200 + k) * TT]) : (short)0;
                    }
                    af[kc] = v;
                }
            }
            float* zout = P.pre1 + (size_t)(t & (RING - 1)) * 12800;
#pragma unroll
            for (int s = 0; s < 4; s++) {
                int g = wv + 16 * s;
                if (g < 50) {
                    f32x4 acc = (f32x4){0.f, 0.f, 0.f, 0.f};
#pragma unroll
                    for (int kc = 0; kc < 7; kc++) acc = mfma16(af[kc], wf[s][kc], acc);
                    int n = g * 16 + col;
                    float bs = P.b1p[n];
#pragma unroll
                    for (int r = 0; r < 4; r++) zout[(quad * 4 + r) * 800 + n] = acc[r] + bs;
                }
            }
        }
        __syncthreads();
        if (tid == 0) { __threadfence(); st_rel(&P.flags[q], 1u); }
    }
}

// ---- C worker: decoder MLP on 64-step blocks (static assignment)
DEV void c_run(const PipeArgs& P, int wid, char* lds) {
    short* hid = (short*)lds;               // [16][128] bf16
    float* outbuf = (float*)(lds + 4096);   // [4][16][208] f32
    const int tid = threadIdx.x;
    const int wv = tid >> 6, lane = tid & 63;
    const int col = lane & 15, quad = lane >> 4;
    unsigned* chain_prog = P.flags + NCHUNK;
    if (tid < 256) { int b = tid >> 4, cc = tid & 15; hid[b * 128 + 112 + cc] = 0; }
    for (int blk = wid; blk < NCHUNK; blk += NC) {
        int t0 = blk * CH, te = min(TT, t0 + CH);
        if (tid == 0) {
            while ((int)ld_acq(chain_prog) < te) __builtin_amdgcn_s_sleep(127);
        }
        __syncthreads();
        for (int tb = t0; tb < te; tb += 4) {
            int nvt = min(4, te - tb);
            for (int dt = 0; dt < nvt; dt++) {
                int t = tb + dt;
                __syncthreads();
                if (wv < 7) {
                    const short* xr = P.h2full + (size_t)t * 3584;
                    f32x4 acc = (f32x4){0.f, 0.f, 0.f, 0.f};
#pragma unroll
                    for (int kc = 0; kc < 7; kc++) {
                        s16x8 a = *(const s16x8*)(xr + col * KP + kc * 32 + quad * 8);
                        s16x8 b = *(const s16x8*)(P.o1w + ((size_t)(wv * 16 + col)) * KP + kc * 32 + quad * 8);
                        acc = mfma16(a, b, acc);
                    }
                    float bs = P.o1b[wv * 16 + col];
#pragma unroll
                    for (int r = 0; r < 4; r++) {
                        float h = acc[r] + bs;
                        h = (h > 0.f) ? h : 0.f;
                        hid[(quad * 4 + r) * 128 + wv * 16 + col] = f2bf(h);
                    }
                }
                __syncthreads();
                if (wv < 13) {
                    f32x4 acc = (f32x4){0.f, 0.f, 0.f, 0.f};
#pragma unroll
                    for (int kc = 0; kc < 4; kc++) {
                        s16x8 a = *(const s16x8*)&hid[col * 128 + kc * 32 + quad * 8];
                        s16x8 b = *(const s16x8*)(P.o2w + ((size_t)(wv * 16 + col)) * 128 + kc * 32 + quad * 8);
                        acc = mfma16(a, b, acc);
                    }
                    int p = wv * 16 + col;
                    if (p < 200) {
                        float bs = P.o2b[p];
#pragma unroll
                        for (int r = 0; r < 4; r++)
                            outbuf[dt * 3328 + (quad * 4 + r) * 208 + p] = acc[r] + bs;
                    }
                }
            }
            __syncthreads();
            for (int idx = tid; idx < 3200; idx += 1024) {
                int b = idx / 200, p = idx % 200;
                float* dp = P.out + ((size_t)(b * 200 + p)) * TT + tb;
                if (nvt == 4) {
                    float4 v = {outbuf[b * 208 + p], outbuf[3328 + b * 208 + p],
                                outbuf[6656 + b * 208 + p], outbuf[9984 + b * 208 + p]};
                    *(float4*)dp = v;
                } else {
                    for (int dt = 0; dt < nvt; dt++) dp[dt] = outbuf[dt * 3328 + b * 208 + p];
                }
            }
            __syncthreads();
        }
    }
}

__global__ __launch_bounds__(1024, 1) void k_pipeline(PipeArgs P) {
    extern __shared__ __align__(16) char pool[];
    const int bid = blockIdx.x;
    if (bid == 0) chain_run(P, pool);
    else if (bid <= NPRE) pre_run(P, bid - 1);
    else c_run(P, bid - 1 - NPRE, pool);
}

// ============================ launcher =====================================
extern "C" void kernel_launch(void* const* d_in, const int* in_sizes, int n_in,
                              void* d_out, int out_size, void* d_ws, size_t ws_size,
                              hipStream_t stream) {
    const float* x_fmri = (const float*)d_in[0];
    const float* x_meg = (const float*)d_in[1];
    const float* conv_w = (const float*)d_in[2];
    const float* conv_b = (const float*)d_in[3];
    const float* bn_g = (const float*)d_in[4];
    const float* bn_b = (const float*)d_in[5];
    const float* w_ih0 = (const float*)d_in[6];
    const float* w_hh0 = (const float*)d_in[7];
    const float* b_ih0 = (const float*)d_in[8];
    const float* b_hh0 = (const float*)d_in[9];
    const float* w_ih1 = (const float*)d_in[10];
    const float* w_hh1 = (const float*)d_in[11];
    const float* b_ih1 = (const float*)d_in[12];
    const float* b_hh1 = (const float*)d_in[13];
    const float* out1_w = (const float*)d_in[14];
    const float* out1_b = (const float*)d_in[15];
    const float* out2_w = (const float*)d_in[16];
    const float* out2_b = (const float*)d_in[17];
    const float* h0 = (const float*)d_in[18];
    const float* c0 = (const float*)d_in[19];

    char* ws = (char*)d_ws;
    size_t off = 0;
    auto alloc = [&](size_t sz) {
        size_t o = off;
        off = (off + sz + 255) & ~(size_t)255;
        return o;
    };
    float* y = (float*)d_out;  // conv output lives in d_out (dead until C writes)
    short* xhatT = (short*)(ws + alloc((size_t)TT * 16 * KP * 2));
    float* scale = (float*)(ws + alloc(200 * 4));
    float* shift = (float*)(ws + alloc(200 * 4));
    short* Wi0p = (short*)(ws + alloc(800 * KP * 2));
    short* Wh0p = (short*)(ws + alloc(800 * KP * 2));
    short* Wi1p = (short*)(ws + alloc(800 * KP * 2));
    short* Wh1p = (short*)(ws + alloc(800 * KP * 2));
    float* b1p = (float*)(ws + alloc(800 * 4));
    float* b2p = (float*)(ws + alloc(800 * 4));
    short* o1wp = (short*)(ws + alloc(112 * KP * 2));
    float* o1bp = (float*)(ws + alloc(112 * 4));
    short* o2wp = (short*)(ws + alloc(208 * 128 * 2));
    float* pre1 = (float*)(ws + alloc((size_t)RING * 12800 * 4));
    short* h2full = (short*)(ws + alloc((size_t)TT * 3584 * 2));
    unsigned* flags = (unsigned*)(ws + alloc(128 * 4));

    k_conv<<<dim3(32, 7, 16), 256, 0, stream>>>(x_fmri, conv_w, conv_b, y);
    k_stats<<<200, 256, 0, stream>>>(y, bn_g, bn_b, scale, shift);
    k_transpose<<<dim3(94, 7, 16), 256, 0, stream>>>(y, scale, shift, xhatT);
    k_prep<<<512, 256, 0, stream>>>(w_ih0, w_hh0, w_ih1, w_hh1, b_ih0, b_hh0, b_ih1, b_hh1,
                                    out1_w, out1_b, out2_w,
                                    Wi0p, Wh0p, Wi1p, Wh1p, b1p, b2p, o1wp, o1bp, o2wp);
    k_init<<<4, 128, 0, stream>>>(flags, 128);

    PipeArgs P;
    P.Wih0 = Wi0p; P.Whh0 = Wh0p; P.Wih1 = Wi1p; P.Whh1 = Wh1p;
    P.o1w = o1wp; P.o2w = o2wp;
    P.b1p = b1p; P.b2p = b2p; P.o1b = o1bp; P.o2b = out2_b;
    P.xhatT = xhatT; P.xmeg = x_meg;
    P.pre1 = pre1; P.h2full = h2full;
    P.flags = flags; P.h0 = h0; P.c0 = c0;
    P.out = (float*)d_out;

    static bool attr_set = []() { return true; }();
    (void)attr_set;
    hipFuncSetAttribute((const void*)k_pipeline,
                        hipFuncAttributeMaxDynamicSharedMemorySize, LDS_BYTES);
    k_pipeline<<<1 + NPRE + NC, 1024, LDS_BYTES, stream>>>(P);
}

// Round 3
// 53168.005 us; speedup vs baseline: 3.7254x; 3.7254x over previous
//
#include <hip/hip_runtime.h>

// ============================================================================
// samba_hemo_to_ele: ConvT1d+GELU+BN -> 2-layer LSTM (T=6000 scan) -> MLP
// Round 3: two 256-thread chain blocks (one per layer, Whh register-resident,
// 1 wave/SIMD => 512-reg budget), chunk-granular (32-step) wavefront pipeline:
//   pre workers -> chain1 -> z2x workers -> chain2 -> C (MLP) workers.
// Round-2 lesson: 1024-thr block capped VGPRs at 64 -> weight spill to scratch.
// ============================================================================

#define DEV static __device__ __forceinline__

typedef short s16x8 __attribute__((ext_vector_type(8)));
typedef float f32x4 __attribute__((ext_vector_type(4)));

#define TCONV 1000
#define TT 6000
#define KP 224        // padded K (7 chunks of 32)
#define XROW 240      // LDS h row pad (shorts)
#define ZROW 804      // zb row pad (dwords); 804%32=4 -> 2-way on MFMA writes
#define RING 512      // pre1 / z2x ring slots (steps)
#define CH 32         // pipeline chunk (steps)
#define NCHUNK 188    // ceil(6000/32)
#define NPRE 6
#define NZ 6
#define NC 8
#define LDS_BYTES 73728

DEV short f2bf(float f) {
    unsigned u = __builtin_bit_cast(unsigned, f);
    unsigned r = (u + 0x7FFFu + ((u >> 16) & 1u)) >> 16;
    return (short)r;
}
DEV int ld_rlx(const unsigned* p) { return (int)__hip_atomic_load(p, __ATOMIC_RELAXED, __HIP_MEMORY_SCOPE_AGENT); }
DEV void acq_fence(const unsigned* p) { (void)__hip_atomic_load(p, __ATOMIC_ACQUIRE, __HIP_MEMORY_SCOPE_AGENT); }
DEV void st_rel(unsigned* p, unsigned v) { __hip_atomic_store(p, v, __ATOMIC_RELEASE, __HIP_MEMORY_SCOPE_AGENT); }
DEV void wait_ge(const unsigned* p, int target) {
    while (ld_rlx(p) < target) __builtin_amdgcn_s_sleep(32);
    acq_fence(p);
}
DEV f32x4 mfma16(s16x8 a, s16x8 b, f32x4 c) { return __builtin_amdgcn_mfma_f32_16x16x32_bf16(a, b, c, 0, 0, 0); }
DEV float sigm(float x) { return 1.f / (1.f + __expf(-x)); }
DEV float tanh_fast(float x) {
    float ax = fabsf(x);
    float e = __expf(-2.f * ax);
    float r = 1.f - 2.f * e / (1.f + e);
    return copysignf(r, x);
}

// ============================ K1: ConvTranspose + GELU =====================
__global__ __launch_bounds__(256) void k_conv(const float* __restrict__ x,
                                              const float* __restrict__ w,
                                              const float* __restrict__ cb,
                                              float* __restrict__ y) {
    __shared__ float ws_[8][32][30];
    __shared__ float xs[8][38];
    const int tt = blockIdx.x, ot = blockIdx.y, b = blockIdx.z;
    const int tid = threadIdx.x;
    const int o_l = tid & 31, tq = tid >> 5;
    const int o = ot * 32 + o_l;
    const int T0base = tt * 32;
    float acc[24];
#pragma unroll
    for (int u = 0; u < 24; u++) acc[u] = 0.f;
    for (int ic = 0; ic < 200; ic += 8) {
        __syncthreads();
        for (int idx = tid; idx < 7680; idx += 256) {
            int ii = idx / 960, rem = idx % 960, oo = rem / 30, kk = rem % 30;
            int og = ot * 32 + oo;
            ws_[ii][oo][kk] = (og < 200) ? w[((size_t)(ic + ii) * 200 + og) * 30 + kk] : 0.f;
        }
        for (int idx = tid; idx < 8 * 36; idx += 256) {
            int ii = idx / 36, m = idx % 36;
            int ti = T0base - 2 + m;
            xs[ii][m] = (ti >= 0 && ti < TCONV) ? x[((size_t)b * 200 + ic + ii) * TCONV + ti] : 0.f;
        }
        __syncthreads();
#pragma unroll
        for (int ii = 0; ii < 8; ii++) {
            float xr[8];
#pragma unroll
            for (int m = 0; m < 8; m++) xr[m] = xs[ii][tq * 4 + m];
#pragma unroll
            for (int r = 0; r < 6; r++) {
#pragma unroll
                for (int j = 0; j < 5; j++) {
                    float wv_ = ws_[ii][o_l][r + 6 * j];
#pragma unroll
                    for (int k = 0; k < 4; k++) acc[r + 6 * k] += xr[k + 4 - j] * wv_;
                }
            }
        }
    }
    if (o < 200) {
        const float bias = cb[o];
        const int tob = tt * 192 + tq * 24;
#pragma unroll
        for (int u = 0; u < 24; u++) {
            int t_o = tob + u;
            if (t_o < TT) {
                float v = acc[u] + bias;
                v = 0.5f * v * (1.f + erff(v * 0.70710678118654752f));
                y[((size_t)b * 200 + o) * TT + t_o] = v;
            }
        }
    }
}

// ============================ K2: BN stats =================================
__global__ __launch_bounds__(256) void k_stats(const float* __restrict__ y,
                                               const float* __restrict__ g,
                                               const float* __restrict__ be,
                                               float* __restrict__ scale,
                                               float* __restrict__ shift) {
    __shared__ float s1[256], s2[256];
    const int c = blockIdx.x, tid = threadIdx.x;
    float a1 = 0.f, a2 = 0.f;
    for (int idx = tid; idx < 16 * TT; idx += 256) {
        int b = idx / TT, t = idx % TT;
        float v = y[((size_t)b * 200 + c) * TT + t];
        a1 += v;
        a2 += v * v;
    }
    s1[tid] = a1; s2[tid] = a2;
    __syncthreads();
    for (int s = 128; s > 0; s >>= 1) {
        if (tid < s) { s1[tid] += s1[tid + s]; s2[tid] += s2[tid + s]; }
        __syncthreads();
    }
    if (tid == 0) {
        float mean = s1[0] / (float)(16 * TT);
        float var = s2[0] / (float)(16 * TT) - mean * mean;
        float istd = rsqrtf(var + 1e-5f);
        float sc = g[c] * istd;
        scale[c] = sc;
        shift[c] = be[c] - mean * sc;
    }
}

// ==================== K3: BN-apply + transpose + bf16 cast =================
__global__ __launch_bounds__(256) void k_transpose(const float* __restrict__ y,
                                                   const float* __restrict__ scale,
                                                   const float* __restrict__ shift,
                                                   short* __restrict__ xhatT) {
    __shared__ float tile[32][65];
    const int tt = blockIdx.x, ct = blockIdx.y, b = blockIdx.z;
    const int tid = threadIdx.x;
    for (int idx = tid; idx < 2048; idx += 256) {
        int c_l = idx >> 6, t_l = idx & 63;
        int c = ct * 32 + c_l, t = tt * 64 + t_l;
        float v = 0.f;
        if (c < 200 && t < TT) v = y[((size_t)b * 200 + c) * TT + t] * scale[c] + shift[c];
        tile[c_l][t_l] = v;
    }
    __syncthreads();
    {
        int t_l = tid >> 2, cq = tid & 3;
        int t = tt * 64 + t_l;
        if (t < TT) {
            short tmp[8];
#pragma unroll
            for (int jj = 0; jj < 8; jj++) tmp[jj] = f2bf(tile[cq * 8 + jj][t_l]);
            *(uint4*)&xhatT[((size_t)t * 16 + b) * KP + ct * 32 + cq * 8] = *(uint4*)tmp;
        }
    }
}

// ==================== K3b: weight prep (permute n'=4j+g, bf16, pad) ========
__global__ void k_prep(const float* wi0, const float* wh0, const float* wi1, const float* wh1,
                       const float* bi0, const float* bh0, const float* bi1, const float* bh1,
                       const float* o1w, const float* o1b, const float* o2w,
                       short* Wi0p, short* Wh0p, short* Wi1p, short* Wh1p,
                       float* b1p, float* b2p, short* o1wp, float* o1bp, short* o2wp) {
    const int TOT = 716800 + 1600 + 25088 + 26624 + 112;
    int i = blockIdx.x * blockDim.x + threadIdx.x;
    int st = gridDim.x * blockDim.x;
    for (; i < TOT; i += st) {
        if (i < 716800) {
            int m = i / 179200, r = i % 179200;
            int np = r / KP, k = r % KP;
            int j = np >> 2, gg = np & 3;
            int row = gg * 200 + j;
            const float* src = (m == 0) ? wi0 : (m == 1) ? wh0 : (m == 2) ? wi1 : wh1;
            short* dst = (m == 0) ? Wi0p : (m == 1) ? Wh0p : (m == 2) ? Wi1p : Wh1p;
            dst[np * KP + k] = (k < 200) ? f2bf(src[row * 200 + k]) : (short)0;
        } else if (i < 718400) {
            int r = i - 716800;
            int which = r / 800, np = r % 800;
            int j = np >> 2, gg = np & 3;
            int row = gg * 200 + j;
            if (which == 0) b1p[np] = bi0[row] + bh0[row];
            else b2p[np] = bi1[row] + bh1[row];
        } else if (i < 743488) {
            int r = i - 718400;
            int o = r / KP, k = r % KP;
            o1wp[o * KP + k] = (o < 100 && k < 200) ? f2bf(o1w[o * 200 + k]) : (short)0;
        } else if (i < 770112) {
            int r = i - 743488;
            int p = r / 128, k = r % 128;
            o2wp[p * 128 + k] = (p < 200 && k < 100) ? f2bf(o2w[p * 100 + k]) : (short)0;
        } else {
            int o = i - 770112;
            o1bp[o] = (o < 100) ? o1b[o] : 0.f;
        }
    }
}

__global__ void k_init(unsigned* p, int n) {
    int i = blockIdx.x * blockDim.x + threadIdx.x;
    int st = gridDim.x * blockDim.x;
    for (; i < n; i += st) p[i] = 0;
}

// ============================ pipeline =====================================
struct PipeArgs {
    const short *Wih0, *Whh0, *Wih1, *Whh1, *o1w, *o2w;
    const float *b1p, *b2p, *o1b, *o2b;
    const short* xhatT;     // [6000][16][224] bf16
    const float* xmeg;
    float* pre1;            // ring [512][16][800] f32 (x-side L1 + bias1)
    float* z2x;             // ring [512][16][800] f32 (x-side L2 + bias2)
    short* h1full;          // [6000][16][224] bf16
    short* h2full;          // [6000][16][224] bf16
    unsigned* flags;        // [0..188) preflags | [188..376) zflags | 376 c1prog | 377 c2prog
    const float *h0, *c0;
    float* out;
};

// ---- generic single-layer LSTM chain (256 threads, Whh register-resident)
DEV void chain_run(const short* __restrict__ Whh, const float* __restrict__ zring,
                   const unsigned* zflags, short* __restrict__ hout,
                   unsigned* prog, const float* h0p, const float* c0p, char* lds) {
    short* X = (short*)lds;                 // [16][240] bf16
    float* cs = (float*)(lds + 7680);       // [16][200] f32
    float* zb = (float*)(lds + 20480);      // [16][804] f32
    const int tid = threadIdx.x;
    const int wv = tid >> 6, lane = tid & 63;
    const int col = lane & 15, quad = lane >> 4;

    for (int i = tid; i < 16 * XROW; i += 256) { int j = i % XROW; X[i] = (j < 200) ? f2bf(h0p[j]) : (short)0; }
    for (int i = tid; i < 3200; i += 256) cs[i] = c0p[i % 200];

    // 50 weight tiles: wave wv holds g = wv + 4*s, s=0..12 (g<50 live)
    s16x8 wf[13][7];
#pragma unroll
    for (int s = 0; s < 13; s++) {
        int g = wv + 4 * s;
#pragma unroll
        for (int kc = 0; kc < 7; kc++) {
            if (g < 50) wf[s][kc] = *(const s16x8*)(Whh + ((size_t)(g * 16 + col)) * KP + kc * 32 + quad * 8);
            else wf[s][kc] = (s16x8){0, 0, 0, 0, 0, 0, 0, 0};
        }
    }
    __syncthreads();

    for (int q = 0; q < NCHUNK; q++) {
        if (tid == 0) wait_ge(&zflags[q], 1);
        __syncthreads();
        const int t0 = q * CH, te = (t0 + CH < TT) ? t0 + CH : TT;
        for (int t = t0; t < te; t++) {
            // prefetch z-in (x-side + bias), consumed after S1
            const float* zin = zring + (size_t)(t & (RING - 1)) * 12800;
            float4 pz[13];
#pragma unroll
            for (int i = 0; i < 13; i++) {
                int idx = tid + 256 * i;
                if (idx < 3200) pz[i] = *(const float4*)(zin + idx * 4);
            }
            // h-side MFMA
            f32x4 acc[13];
#pragma unroll
            for (int s = 0; s < 13; s++) acc[s] = (f32x4){0.f, 0.f, 0.f, 0.f};
#pragma unroll
            for (int kc = 0; kc < 7; kc++) {
                s16x8 a = *(const s16x8*)&X[col * XROW + kc * 32 + quad * 8];
#pragma unroll
                for (int s = 0; s < 13; s++) {
                    int g = wv + 4 * s;
                    if (g < 50) acc[s] = mfma16(a, wf[s][kc], acc[s]);
                }
            }
#pragma unroll
            for (int s = 0; s < 13; s++) {
                int g = wv + 4 * s;
                if (g < 50) {
#pragma unroll
                    for (int r = 0; r < 4; r++) zb[(quad * 4 + r) * ZROW + g * 16 + col] = acc[s][r];
                }
            }
            __syncthreads();  // S1
            // gates
#pragma unroll
            for (int i = 0; i < 13; i++) {
                int idx = tid + 256 * i;
                if (idx < 3200) {
                    int b = idx / 200, j = idx % 200;
                    float4 z4 = *(const float4*)&zb[b * ZROW + j * 4];
                    float4 p4 = pz[i];
                    float ig = sigm(z4.x + p4.x);
                    float fg = sigm(z4.y + p4.y);
                    float gg = tanh_fast(z4.z + p4.z);
                    float og = sigm(z4.w + p4.w);
                    float c = fg * cs[b * 200 + j] + ig * gg;
                    cs[b * 200 + j] = c;
                    X[b * XROW + j] = f2bf(og * tanh_fast(c));
                }
            }
            __syncthreads();  // S2
            // h -> global (read-only on X; overlaps next step's MFMA)
            short* dst = hout + (size_t)t * 3584;
#pragma unroll
            for (int i = 0; i < 2; i++) {
                int idx = tid + 256 * i;
                if (idx < 448) {
                    int b = idx / 28, cc = idx % 28;
                    *(uint4*)(dst + b * 224 + cc * 8) = *(const uint4*)(X + b * XROW + cc * 8);
                }
            }
        }
        __syncthreads();  // drains vmcnt for all waves before release
        if (tid == 0) { __threadfence(); st_rel(prog, (unsigned)te); }
    }
}

// ---- worker GEMM step: zout[16][800] = arow(bf16 [16][224]) @ W^T + bias
DEV void wgemm_step(const s16x8 wf[13][7], const float* __restrict__ bias,
                    const short* __restrict__ arow, float* __restrict__ zout,
                    int wv, int col, int quad) {
    s16x8 af[7];
#pragma unroll
    for (int kc = 0; kc < 7; kc++)
        af[kc] = *(const s16x8*)(arow + col * KP + kc * 32 + quad * 8);
    f32x4 acc[13];
#pragma unroll
    for (int s = 0; s < 13; s++) acc[s] = (f32x4){0.f, 0.f, 0.f, 0.f};
#pragma unroll
    for (int kc = 0; kc < 7; kc++) {
#pragma unroll
        for (int s = 0; s < 13; s++) {
            int g = wv + 4 * s;
            if (g < 50) acc[s] = mfma16(af[kc], wf[s][kc], acc[s]);
        }
    }
#pragma unroll
    for (int s = 0; s < 13; s++) {
        int g = wv + 4 * s;
        if (g < 50) {
            int n = g * 16 + col;
            float bs = bias[n];
#pragma unroll
            for (int r = 0; r < 4; r++) zout[(quad * 4 + r) * 800 + n] = acc[s][r] + bs;
        }
    }
}

DEV void load_wtiles(s16x8 wf[13][7], const short* W, int wv, int col, int quad) {
#pragma unroll
    for (int s = 0; s < 13; s++) {
        int g = wv + 4 * s;
#pragma unroll
        for (int kc = 0; kc < 7; kc++) {
            if (g < 50) wf[s][kc] = *(const s16x8*)(W + ((size_t)(g * 16 + col)) * KP + kc * 32 + quad * 8);
            else wf[s][kc] = (s16x8){0, 0, 0, 0, 0, 0, 0, 0};
        }
    }
}

// ---- pre worker: pre1[t] = inputs[t] @ Wih0^T + bias1
DEV void pre_run(const PipeArgs& P, int wid) {
    const int tid = threadIdx.x;
    const int wv = tid >> 6, lane = tid & 63;
    const int col = lane & 15, quad = lane >> 4;
    s16x8 wf[13][7];
    load_wtiles(wf, P.Wih0, wv, col, quad);
    const unsigned* c1prog = P.flags + 2 * NCHUNK;
    for (int q = wid; q < NCHUNK; q += NPRE) {
        int t0 = q * CH, te = (t0 + CH < TT) ? t0 + CH : TT;
        int lim = t0 + CH - RING;  // ring space
        if (lim > 0) {
            if (tid == 0) wait_ge(c1prog, lim);
            __syncthreads();
        }
        for (int t = t0; t < te; t++) {
            float* zout = P.pre1 + (size_t)(t & (RING - 1)) * 12800;
            if (t > 0) {
                wgemm_step(wf, P.b1p, P.xhatT + (size_t)(t - 1) * 3584, zout, wv, col, quad);
            } else {
                // inputs[0] = x_meg[:, :, 0]
                s16x8 af[7];
#pragma unroll
                for (int kc = 0; kc < 7; kc++) {
                    s16x8 v;
#pragma unroll
                    for (int j = 0; j < 8; j++) {
                        int k = kc * 32 + quad * 8 + j;
                        v[j] = (k < 200) ? f2bf(P.xmeg[((size_t)col * 200 + k) * TT]) : (short)0;
                    }
                    af[kc] = v;
                }
                f32x4 acc[13];
#pragma unroll
                for (int s = 0; s < 13; s++) acc[s] = (f32x4){0.f, 0.f, 0.f, 0.f};
#pragma unroll
                for (int kc = 0; kc < 7; kc++)
#pragma unroll
                    for (int s = 0; s < 13; s++) {
                        int g = wv + 4 * s;
                        if (g < 50) acc[s] = mfma16(af[kc], wf[s][kc], acc[s]);
                    }
#pragma unroll
                for (int s = 0; s < 13; s++) {
                    int g = wv + 4 * s;
                    if (g < 50) {
                        int n = g * 16 + col;
                        float bs = P.b1p[n];
#pragma unroll
                        for (int r = 0; r < 4; r++) zout[(quad * 4 + r) * 800 + n] = acc[s][r] + bs;
                    }
                }
            }
        }
        __syncthreads();
        if (tid == 0) { __threadfence(); st_rel(&P.flags[q], 1u); }
    }
}

// ---- z2x worker: z2x[t] = h1[t] @ Wih1^T + bias2
DEV void z2x_run(const PipeArgs& P, int wid) {
    const int tid = threadIdx.x;
    const int wv = tid >> 6, lane = tid & 63;
    const int col = lane & 15, quad = lane >> 4;
    s16x8 wf[13][7];
    load_wtiles(wf, P.Wih1, wv, col, quad);
    const unsigned* c1prog = P.flags + 2 * NCHUNK;
    const unsigned* c2prog = P.flags + 2 * NCHUNK + 1;
    for (int q = wid; q < NCHUNK; q += NZ) {
        int t0 = q * CH, te = (t0 + CH < TT) ? t0 + CH : TT;
        if (tid == 0) {
            wait_ge(c1prog, te);               // h1 ready
            int lim = t0 + CH - RING;          // ring space
            if (lim > 0) wait_ge(c2prog, lim);
        }
        __syncthreads();
        for (int t = t0; t < te; t++)
            wgemm_step(wf, P.b2p, P.h1full + (size_t)t * 3584,
                       P.z2x + (size_t)(t & (RING - 1)) * 12800, wv, col, quad);
        __syncthreads();
        if (tid == 0) { __threadfence(); st_rel(&P.flags[NCHUNK + q], 1u); }
    }
}

// ---- C worker: decoder MLP over chunks
DEV void c_run(const PipeArgs& P, int wid, char* lds) {
    short* hid = (short*)lds;               // [16][128] bf16
    float* outbuf = (float*)(lds + 4096);   // [4][16][208] f32
    const int tid = threadIdx.x;
    const int wv = tid >> 6, lane = tid & 63;
    const int col = lane & 15, quad = lane >> 4;
    const unsigned* c2prog = P.flags + 2 * NCHUNK + 1;
    // o1: 7 tiles (g=wv+4s, s<2); o2: 13 tiles (g=wv+4s, s<4)
    s16x8 w1[2][7], w2[4][4];
#pragma unroll
    for (int s = 0; s < 2; s++) {
        int g = wv + 4 * s;
#pragma unroll
        for (int kc = 0; kc < 7; kc++)
            w1[s][kc] = (g < 7) ? *(const s16x8*)(P.o1w + ((size_t)(g * 16 + col)) * KP + kc * 32 + quad * 8)
                                : (s16x8){0, 0, 0, 0, 0, 0, 0, 0};
    }
#pragma unroll
    for (int s = 0; s < 4; s++) {
        int g = wv + 4 * s;
#pragma unroll
        for (int kc = 0; kc < 4; kc++)
            w2[s][kc] = (g < 13) ? *(const s16x8*)(P.o2w + ((size_t)(g * 16 + col)) * 128 + kc * 32 + quad * 8)
                                 : (s16x8){0, 0, 0, 0, 0, 0, 0, 0};
    }
    if (tid < 256) { int b = tid >> 4, cc = tid & 15; hid[b * 128 + 112 + cc] = 0; }
    for (int q = wid; q < NCHUNK; q += NC) {
        int t0 = q * CH, te = (t0 + CH < TT) ? t0 + CH : TT;
        if (tid == 0) wait_ge(c2prog, te);
        __syncthreads();
        for (int tb = t0; tb < te; tb += 4) {
            int nvt = (te - tb < 4) ? te - tb : 4;
            for (int dt = 0; dt < nvt; dt++) {
                int t = tb + dt;
                __syncthreads();  // hid reuse guard
                const short* xr = P.h2full + (size_t)t * 3584;
                s16x8 af[7];
#pragma unroll
                for (int kc = 0; kc < 7; kc++)
                    af[kc] = *(const s16x8*)(xr + col * KP + kc * 32 + quad * 8);
#pragma unroll
                for (int s = 0; s < 2; s++) {
                    int g = wv + 4 * s;
                    if (g < 7) {
                        f32x4 acc = (f32x4){0.f, 0.f, 0.f, 0.f};
#pragma unroll
                        for (int kc = 0; kc < 7; kc++) acc = mfma16(af[kc], w1[s][kc], acc);
                        int n = g * 16 + col;
                        float bs = P.o1b[n];
#pragma unroll
                        for (int r = 0; r < 4; r++) {
                            float h = acc[r] + bs;
                            h = (h > 0.f) ? h : 0.f;
                            hid[(quad * 4 + r) * 128 + n] = f2bf(h);
                        }
                    }
                }
                __syncthreads();
#pragma unroll
                for (int s = 0; s < 4; s++) {
                    int g = wv + 4 * s;
                    if (g < 13) {
                        f32x4 acc = (f32x4){0.f, 0.f, 0.f, 0.f};
#pragma unroll
                        for (int kc = 0; kc < 4; kc++) {
                            s16x8 a = *(const s16x8*)&hid[col * 128 + kc * 32 + quad * 8];
                            acc = mfma16(a, w2[s][kc], acc);
                        }
                        int p = g * 16 + col;
                        if (p < 200) {
                            float bs = P.o2b[p];
#pragma unroll
                            for (int r = 0; r < 4; r++)
                                outbuf[dt * 3328 + (quad * 4 + r) * 208 + p] = acc[r] + bs;
                        }
                    }
                }
            }
            __syncthreads();
            for (int idx = tid; idx < 3200; idx += 256) {
                int b = idx / 200, p = idx % 200;
                float* dp = P.out + ((size_t)(b * 200 + p)) * TT + tb;
                if (nvt == 4) {
                    float4 v = {outbuf[b * 208 + p], outbuf[3328 + b * 208 + p],
                                outbuf[6656 + b * 208 + p], outbuf[9984 + b * 208 + p]};
                    *(float4*)dp = v;
                } else {
                    for (int dt = 0; dt < nvt; dt++) dp[dt] = outbuf[dt * 3328 + b * 208 + p];
                }
            }
            __syncthreads();
        }
    }
}

__global__ __launch_bounds__(256, 1) void k_pipeline(PipeArgs P) {
    extern __shared__ __align__(16) char pool[];
    const int bid = blockIdx.x;
    if (bid == 0) {
        chain_run(P.Whh0, P.pre1, P.flags, P.h1full, P.flags + 2 * NCHUNK, P.h0, P.c0, pool);
    } else if (bid == 1) {
        chain_run(P.Whh1, P.z2x, P.flags + NCHUNK, P.h2full, P.flags + 2 * NCHUNK + 1,
                  P.h0 + 200, P.c0 + 200, pool);
    } else if (bid < 2 + NPRE) {
        pre_run(P, bid - 2);
    } else if (bid < 2 + NPRE + NZ) {
        z2x_run(P, bid - 2 - NPRE);
    } else {
        c_run(P, bid - 2 - NPRE - NZ, pool);
    }
}

// ============================ launcher =====================================
extern "C" void kernel_launch(void* const* d_in, const int* in_sizes, int n_in,
                              void* d_out, int out_size, void* d_ws, size_t ws_size,
                              hipStream_t stream) {
    const float* x_fmri = (const float*)d_in[0];
    const float* x_meg = (const float*)d_in[1];
    const float* conv_w = (const float*)d_in[2];
    const float* conv_b = (const float*)d_in[3];
    const float* bn_g = (const float*)d_in[4];
    const float* bn_b = (const float*)d_in[5];
    const float* w_ih0 = (const float*)d_in[6];
    const float* w_hh0 = (const float*)d_in[7];
    const float* b_ih0 = (const float*)d_in[8];
    const float* b_hh0 = (const float*)d_in[9];
    const float* w_ih1 = (const float*)d_in[10];
    const float* w_hh1 = (const float*)d_in[11];
    const float* b_ih1 = (const float*)d_in[12];
    const float* b_hh1 = (const float*)d_in[13];
    const float* out1_w = (const float*)d_in[14];
    const float* out1_b = (const float*)d_in[15];
    const float* out2_w = (const float*)d_in[16];
    const float* out2_b = (const float*)d_in[17];
    const float* h0 = (const float*)d_in[18];
    const float* c0 = (const float*)d_in[19];

    char* ws = (char*)d_ws;
    size_t off = 0;
    auto alloc = [&](size_t sz) {
        size_t o = off;
        off = (off + sz + 255) & ~(size_t)255;
        return o;
    };
    float* y = (float*)d_out;  // conv output in d_out (dead until C writes)
    short* xhatT = (short*)(ws + alloc((size_t)TT * 3584 * 2));
    short* h1full = (short*)(ws + alloc((size_t)TT * 3584 * 2));
    short* h2full = (short*)(ws + alloc((size_t)TT * 3584 * 2));
    float* scale = (float*)(ws + alloc(200 * 4));
    float* shift = (float*)(ws + alloc(200 * 4));
    short* Wi0p = (short*)(ws + alloc(800 * KP * 2));
    short* Wh0p = (short*)(ws + alloc(800 * KP * 2));
    short* Wi1p = (short*)(ws + alloc(800 * KP * 2));
    short* Wh1p = (short*)(ws + alloc(800 * KP * 2));
    float* b1p = (float*)(ws + alloc(800 * 4));
    float* b2p = (float*)(ws + alloc(800 * 4));
    short* o1wp = (short*)(ws + alloc(112 * KP * 2));
    float* o1bp = (float*)(ws + alloc(112 * 4));
    short* o2wp = (short*)(ws + alloc(208 * 128 * 2));
    float* pre1 = (float*)(ws + alloc((size_t)RING * 12800 * 4));
    float* z2x = (float*)(ws + alloc((size_t)RING * 12800 * 4));
    unsigned* flags = (unsigned*)(ws + alloc(512 * 4));

    k_conv<<<dim3(32, 7, 16), 256, 0, stream>>>(x_fmri, conv_w, conv_b, y);
    k_stats<<<200, 256, 0, stream>>>(y, bn_g, bn_b, scale, shift);
    k_transpose<<<dim3(94, 7, 16), 256, 0, stream>>>(y, scale, shift, xhatT);
    k_prep<<<512, 256, 0, stream>>>(w_ih0, w_hh0, w_ih1, w_hh1, b_ih0, b_hh0, b_ih1, b_hh1,
                                    out1_w, out1_b, out2_w,
                                    Wi0p, Wh0p, Wi1p, Wh1p, b1p, b2p, o1wp, o1bp, o2wp);
    k_init<<<4, 128, 0, stream>>>(flags, 512);

    PipeArgs P;
    P.Wih0 = Wi0p; P.Whh0 = Wh0p; P.Wih1 = Wi1p; P.Whh1 = Wh1p;
    P.o1w = o1wp; P.o2w = o2wp;
    P.b1p = b1p; P.b2p = b2p; P.o1b = o1bp; P.o2b = out2_b;
    P.xhatT = xhatT; P.xmeg = x_meg;
    P.pre1 = pre1; P.z2x = z2x; P.h1full = h1full; P.h2full = h2full;
    P.flags = flags; P.h0 = h0; P.c0 = c0;
    P.out = (float*)d_out;

    hipFuncSetAttribute((const void*)k_pipeline,
                        hipFuncAttributeMaxDynamicSharedMemorySize, LDS_BYTES);
    k_pipeline<<<2 + NPRE + NZ + NC, 256, LDS_BYTES, stream>>>(P);
}